// Round 7
// baseline (749.886 us; speedup 1.0000x reference)
//
#include <hip/hip_runtime.h>

constexpr int BB = 4096;   // batch
constexpr int TT = 2048;   // time
constexpr int HH = 32;     // hidden
constexpr int GE = 16;     // elements per block (MFMA N)

typedef float v2f __attribute__((ext_vector_type(2)));
typedef float v4f __attribute__((ext_vector_type(4)));
typedef float f32x4 __attribute__((ext_vector_type(4)));
typedef _Float16 f16x8 __attribute__((ext_vector_type(8)));
typedef _Float16 v8h __attribute__((ext_vector_type(8)));

// ---------- fast math ----------
__device__ __forceinline__ float fexp2(float x) { return __builtin_amdgcn_exp2f(x); }
__device__ __forceinline__ float frcp(float x)  { return __builtin_amdgcn_rcpf(x); }
__device__ __forceinline__ float fsigmoid(float x) {
    return frcp(1.0f + fexp2(x * -1.4426950408889634f));
}
__device__ __forceinline__ float felu(float x) {
    return x > 0.0f ? x : (fexp2(x * 1.4426950408889634f) - 1.0f);
}

// ---------- kernel 1: counting sort of batch indices by length, descending ----------
__global__ void sort_by_len_kernel(const int* __restrict__ lengths, int* __restrict__ perm) {
    __shared__ int hist[TT];
    __shared__ int csum[256];
    const int tid = threadIdx.x;
    for (int i = tid; i < TT; i += 256) hist[i] = 0;
    __syncthreads();
    for (int i = tid; i < BB; i += 256) atomicAdd(&hist[TT - lengths[i]], 1);
    __syncthreads();
    const int base = tid * 8;
    int loc[8];
    int s = 0;
#pragma unroll
    for (int j = 0; j < 8; ++j) { loc[j] = hist[base + j]; s += loc[j]; }
    csum[tid] = s;
    __syncthreads();
    for (int off = 1; off < 256; off <<= 1) {
        int v = (tid >= off) ? csum[tid - off] : 0;
        __syncthreads();
        csum[tid] += v;
        __syncthreads();
    }
    int run = csum[tid] - s;
#pragma unroll
    for (int j = 0; j < 8; ++j) { int t = loc[j]; hist[base + j] = run; run += t; }
    __syncthreads();
    for (int i = tid; i < BB; i += 256) {
        int pos = atomicAdd(&hist[TT - lengths[i]], 1);
        perm[pos] = i;
    }
}

// ---------- kernel 2: MFMA group-batched backward LSTM, 8 waves, chain-shaved ----------
// r6 measured wall/step = 640 cy, chain-bound (VALUBusy 25%, issue hidden).
// Chain = bar-release -> DS queue + ds_read(120) -> MFMA(50) -> gate trans
// (~120) -> c -> tanh-c trans (~110) -> write + lgkm drain -> barrier.
// This round shaves the movement terms, arithmetic untouched (bit-exact,
// absmax must stay exactly 1.953125e-3):
//  1) xe: one ds_read_b128 per 4 steps into regs (post-barrier DS ops/wave
//     2.0 -> 1.25; less last-wave DS queueing, which the barrier re-syncs
//     everyone to).
//  2) raw lgkmcnt-only barrier (asm + s_barrier + compiler fences) -- no
//     vmcnt(0) drain per step.
//  3) x global->reg prefetch (issued 64 steps early), deposit to the
//     double-buffered xls right before the normal step barrier: HBM/L3
//     latency fully off-chain, boundary stall removed.
// Mapping unchanged from r6 (verified): wave w owns units 4w..4w+3; A row
// r=lane&15: gate s=r&3, unit 4w+(r>>2); k = 8*(lane>>4)+j both operands;
// D row 4*lg+i = gates of unit ud=4w+lg, col e=lane&15.
__global__ __attribute__((amdgpu_flat_work_group_size(512, 512)))
void lstm_kernel(const float* __restrict__ x, const int* __restrict__ lengths,
                 const float* __restrict__ w_ih, const float* __restrict__ w_hh,
                 const float* __restrict__ b_ih, const float* __restrict__ b_hh,
                 const float* __restrict__ fc_w, const float* __restrict__ fc_b,
                 const float* __restrict__ fc2_w, const float* __restrict__ fc2_b,
                 float* __restrict__ out, const int* __restrict__ perm) {
    __shared__ __align__(16) _Float16 hb[2][GE][40];  // h, f16, padded, dbuf
    __shared__ __align__(16) float xls[2][GE][68];    // x chunk, padded, dbuf
    __shared__ int barr[GE];
    __shared__ int Llds[GE];

    const int tid  = threadIdx.x;
    const int wv   = tid >> 6;        // wave 0..7
    const int lane = tid & 63;
    const int lg   = lane >> 4;       // lane group 0..3
    const int e    = lane & 15;       // element (MFMA col)

    const int g = blockIdx.x;
    if (tid < GE) {
        const int b = perm ? perm[GE * g + tid] : (GE * g + tid);
        barr[tid] = b;
        Llds[tid] = lengths[b];
    }
    for (int i = tid; i < 2 * GE * 40; i += 512) ((_Float16*)hb)[i] = (_Float16)0.0f;
    __syncthreads();
    // wave-uniform maxL: every thread reduces the 16 lengths (broadcast reads)
    int maxL = 0;
#pragma unroll
    for (int i = 0; i < GE; ++i) maxL = max(maxL, Llds[i]);
    const int Lme = Llds[e];

    const float NL2E = -1.4426950408889634f;

    // ---- A fragment (loaded once)
    const int r  = lane & 15;
    const int sg = r & 3;
    const int ua = 4 * wv + (r >> 2);
    const float asc = (sg == 2) ? 2.0f * NL2E : NL2E;
    f16x8 afr;
    {
        const v4f* wp = reinterpret_cast<const v4f*>(w_hh + (sg * 32 + ua) * 32 + 8 * lg);
        const v4f wa = wp[0], wb = wp[1];
        afr = (f16x8){(_Float16)(wa.x * asc), (_Float16)(wa.y * asc),
                      (_Float16)(wa.z * asc), (_Float16)(wa.w * asc),
                      (_Float16)(wb.x * asc), (_Float16)(wb.y * asc),
                      (_Float16)(wb.z * asc), (_Float16)(wb.w * asc)};
    }
    // ---- D-row constants (gates i of unit ud)
    const int ud = 4 * wv + lg;
    float wih_[4], bs_[4];
#pragma unroll
    for (int i = 0; i < 4; ++i) {
        const float scd = (i == 2) ? 2.0f * NL2E : NL2E;
        wih_[i] = w_ih[i * 32 + ud] * scd;
        bs_[i]  = (b_ih[i * 32 + ud] + b_hh[i * 32 + ud]) * scd;
    }

    float c = 0.0f;
    int p = 0;

    // ---- x staging: 512 thr x v2f covers 16 el x 64 floats
    const int es = tid >> 5;           // element 0..15
    const int j2 = (tid & 31) * 2;     // float offset 0..62
    const float* xbase = x + (size_t)barr[es] * TT + j2;

    int s = maxL - 1;
    const int tb0 = s & ~63;
    {   // chunk 0: load + deposit into xls[0]
        const v2f xr = *reinterpret_cast<const v2f*>(xbase + tb0);
        *reinterpret_cast<v2f*>(&xls[0][es][j2]) = xr;
    }
    int qx = 0;
    v2f xpref = (v2f)(0.0f);           // prefetch chunk 1 (64 steps early)
    if (tb0 >= 64) xpref = *reinterpret_cast<const v2f*>(xbase + tb0 - 64);
    asm volatile("s_waitcnt lgkmcnt(0)" ::: "memory");
    __builtin_amdgcn_s_barrier();
    asm volatile("" ::: "memory");

    v4f x4 = (v4f)(0.0f);              // 4 staged xe values (b128 per 4 steps)
    for (; s >= 0; --s) {
        const int sl = s & 63;
        if ((s & 3) == 3 || s == maxL - 1) {
            x4 = *reinterpret_cast<const v4f*>(&xls[qx][e][sl & ~3]);
        }
        const float xe = x4[s & 3];

        // B fragment: h[k = 8*lg + j][e], contiguous 16B
        const f16x8 bf = *reinterpret_cast<const f16x8*>(&hb[p][e][lg * 8]);
        f32x4 C;
#pragma unroll
        for (int i = 0; i < 4; ++i) C[i] = fmaf(wih_[i], xe, bs_[i]);
        const f32x4 D = __builtin_amdgcn_mfma_f32_16x16x32_f16(afr, bf, C, 0, 0, 0);
        const bool act = (s < Lme);

        // ---- cell update (bit-identical to r5/r6)
        const float Ei = fexp2(D[0]), Ef = fexp2(D[1]);
        const float Eg = fexp2(D[2]), Eo = fexp2(D[3]);
        const float R1 = frcp((1.0f + Ei) * (1.0f + Eg));
        const float ig = (1.0f - Eg) * R1;
        const float R2 = frcp((1.0f + Ef) * (1.0f + Eo));
        const float sf = (1.0f + Eo) * R2;
        const float so = (1.0f + Ef) * R2;
        const float cn = fmaf(sf, c, ig);
        c = act ? cn : c;
        const float tc = 1.0f - 2.0f * frcp(1.0f + fexp2(c * 2.8853900817779268f));
        const float hn = act ? (so * tc) : 0.0f;

        hb[p ^ 1][e][ud] = (_Float16)hn;

        if (sl == 0 && s > 0) {
            // deposit prefetched chunk [s-64, s-1]; its global load was issued
            // 64 steps ago (vmcnt wait here is free)
            *reinterpret_cast<v2f*>(&xls[qx ^ 1][es][j2]) = xpref;
            if (s >= 128)
                xpref = *reinterpret_cast<const v2f*>(xbase + s - 128);
            qx ^= 1;
        }
        asm volatile("s_waitcnt lgkmcnt(0)" ::: "memory");
        __builtin_amdgcn_s_barrier();
        asm volatile("" ::: "memory");
        p ^= 1;
    }

    // ---- head: wave wv handles elements 2wv, 2wv+1
    for (int e2 = 2 * wv; e2 < 2 * wv + 2; ++e2) {
        float hf[32];
        const v8h* hp8 = reinterpret_cast<const v8h*>(&hb[p][e2][0]);
#pragma unroll
        for (int q4 = 0; q4 < 4; ++q4) {
            const v8h hh = hp8[q4];
#pragma unroll
            for (int j = 0; j < 8; ++j) hf[8 * q4 + j] = (float)hh[j];
        }
        float a = fc_b[lane];
        const v4f* fp = reinterpret_cast<const v4f*>(fc_w + lane * 32);
#pragma unroll
        for (int q4 = 0; q4 < 8; ++q4) {
            const v4f f = fp[q4];
            a = fmaf(f.x, hf[4 * q4 + 0], a);
            a = fmaf(f.y, hf[4 * q4 + 1], a);
            a = fmaf(f.z, hf[4 * q4 + 2], a);
            a = fmaf(f.w, hf[4 * q4 + 3], a);
        }
        float partial = felu(a) * fc2_w[lane];
#pragma unroll
        for (int m = 32; m >= 1; m >>= 1) partial += __shfl_xor(partial, m, 64);
        if (lane == 0) out[barr[e2]] = fsigmoid(partial + fc2_b[0]);
    }
}

extern "C" void kernel_launch(void* const* d_in, const int* in_sizes, int n_in,
                              void* d_out, int out_size, void* d_ws, size_t ws_size,
                              hipStream_t stream) {
    const float* x       = (const float*)d_in[0];
    const int*   lengths = (const int*)d_in[1];
    const float* w_ih    = (const float*)d_in[2];
    const float* w_hh    = (const float*)d_in[3];
    const float* b_ih    = (const float*)d_in[4];
    const float* b_hh    = (const float*)d_in[5];
    const float* fc_w    = (const float*)d_in[6];
    const float* fc_b    = (const float*)d_in[7];
    const float* fc2_w   = (const float*)d_in[8];
    const float* fc2_b   = (const float*)d_in[9];
    float* out = (float*)d_out;

    int* perm = nullptr;
    if (ws_size >= (size_t)BB * sizeof(int)) {
        perm = (int*)d_ws;
        hipLaunchKernelGGL(sort_by_len_kernel, dim3(1), dim3(256), 0, stream, lengths, perm);
    }
    hipLaunchKernelGGL(lstm_kernel, dim3(BB / GE), dim3(512), 0, stream,
                       x, lengths, w_ih, w_hh, b_ih, b_hh,
                       fc_w, fc_b, fc2_w, fc2_b, out, perm);
}

// Round 8
// 591.105 us; speedup vs baseline: 1.2686x; 1.2686x over previous
//
#include <hip/hip_runtime.h>

constexpr int BB = 4096;   // batch
constexpr int TT = 2048;   // time
constexpr int HH = 32;     // hidden
constexpr int GE = 16;     // elements per block (MFMA N)

typedef float v2f __attribute__((ext_vector_type(2)));
typedef float v4f __attribute__((ext_vector_type(4)));
typedef float f32x4 __attribute__((ext_vector_type(4)));
typedef _Float16 f16x8 __attribute__((ext_vector_type(8)));
typedef _Float16 v8h __attribute__((ext_vector_type(8)));

// ---------- fast math ----------
__device__ __forceinline__ float fexp2(float x) { return __builtin_amdgcn_exp2f(x); }
__device__ __forceinline__ float frcp(float x)  { return __builtin_amdgcn_rcpf(x); }
__device__ __forceinline__ float fsigmoid(float x) {
    return frcp(1.0f + fexp2(x * -1.4426950408889634f));
}
__device__ __forceinline__ float felu(float x) {
    return x > 0.0f ? x : (fexp2(x * 1.4426950408889634f) - 1.0f);
}

// ---------- kernel 1: counting sort of batch indices by length, descending ----------
__global__ void sort_by_len_kernel(const int* __restrict__ lengths, int* __restrict__ perm) {
    __shared__ int hist[TT];
    __shared__ int csum[256];
    const int tid = threadIdx.x;
    for (int i = tid; i < TT; i += 256) hist[i] = 0;
    __syncthreads();
    for (int i = tid; i < BB; i += 256) atomicAdd(&hist[TT - lengths[i]], 1);
    __syncthreads();
    const int base = tid * 8;
    int loc[8];
    int s = 0;
#pragma unroll
    for (int j = 0; j < 8; ++j) { loc[j] = hist[base + j]; s += loc[j]; }
    csum[tid] = s;
    __syncthreads();
    for (int off = 1; off < 256; off <<= 1) {
        int v = (tid >= off) ? csum[tid - off] : 0;
        __syncthreads();
        csum[tid] += v;
        __syncthreads();
    }
    int run = csum[tid] - s;
#pragma unroll
    for (int j = 0; j < 8; ++j) { int t = loc[j]; hist[base + j] = run; run += t; }
    __syncthreads();
    for (int i = tid; i < BB; i += 256) {
        int pos = atomicAdd(&hist[TT - lengths[i]], 1);
        perm[pos] = i;
    }
}

// ---------- kernel 2: MFMA group-batched backward LSTM, 8 waves (r6 + 2 fixes) ----------
// r7 regressed (confounded: runtime-indexed vector -> cndmask/scratch + branchy
// restructure defeated LLVM's schedule). This round: EXACT r6 body (546us,
// wall/step 640cy) + two surgical, branch-shape-preserving changes:
//  1) xls padding 68 -> 66 floats: xe read bank = (2e+sl)%32, 16 distinct
//     -> conflict-free (was 2-way; ~32cy/step of SQ_LDS_BANK_CONFLICT on wall).
//  2) x chunk register-prefetch: chunk preloaded to v2f regs before the loop;
//     boundary deposits regs->LDS (no global latency on chain), barrier, then
//     issues the NEXT chunk's load, which drains at the next steady-step
//     barrier (~640cy later) -> HBM latency (~900cy, once per 64 steps) mostly
//     off the chain (was fully on it).
// Arithmetic untouched -> absmax must stay exactly 1.953125e-3.
// Mapping (verified r5/r6): wave w owns units 4w..4w+3; A row r=lane&15:
// gate s=r&3, unit 4w+(r>>2); k = 8*(lane>>4)+j for both operands;
// D row 4*lg+i = gates of unit ud=4w+lg, col e=lane&15.
__global__ __attribute__((amdgpu_flat_work_group_size(512, 512)))
void lstm_kernel(const float* __restrict__ x, const int* __restrict__ lengths,
                 const float* __restrict__ w_ih, const float* __restrict__ w_hh,
                 const float* __restrict__ b_ih, const float* __restrict__ b_hh,
                 const float* __restrict__ fc_w, const float* __restrict__ fc_b,
                 const float* __restrict__ fc2_w, const float* __restrict__ fc2_b,
                 float* __restrict__ out, const int* __restrict__ perm) {
    __shared__ __align__(16) _Float16 hb[2][GE][40];  // h, f16, padded rows, dbuf
    __shared__ __align__(16) float xls[GE][66];       // x chunk; 66 = conflict-free
    __shared__ int barr[GE];
    __shared__ int Llds[GE];
    __shared__ int maxLs;

    const int tid  = threadIdx.x;
    const int wv   = tid >> 6;        // wave 0..7
    const int lane = tid & 63;
    const int lg   = lane >> 4;       // lane group 0..3
    const int e    = lane & 15;       // element (MFMA col)

    const int g = blockIdx.x;
    if (tid < GE) {
        const int b = perm ? perm[GE * g + tid] : (GE * g + tid);
        barr[tid] = b;
        Llds[tid] = lengths[b];
    }
    for (int i = tid; i < 2 * GE * 40; i += 512) ((_Float16*)hb)[i] = (_Float16)0.0f;
    __syncthreads();
    if (tid == 0) {
        int m = 0;
        for (int i = 0; i < GE; ++i) m = max(m, Llds[i]);
        maxLs = m;
    }
    __syncthreads();
    const int maxL = maxLs;
    const int Lme  = Llds[e];

    const float NL2E = -1.4426950408889634f;

    // ---- A fragment (loaded once)
    const int r  = lane & 15;
    const int sg = r & 3;
    const int ua = 4 * wv + (r >> 2);
    const float asc = (sg == 2) ? 2.0f * NL2E : NL2E;   // g row: tanh scaling
    f16x8 afr;
    {
        const v4f* wp = reinterpret_cast<const v4f*>(w_hh + (sg * 32 + ua) * 32 + 8 * lg);
        const v4f wa = wp[0], wb = wp[1];
        afr = (f16x8){(_Float16)(wa.x * asc), (_Float16)(wa.y * asc),
                      (_Float16)(wa.z * asc), (_Float16)(wa.w * asc),
                      (_Float16)(wb.x * asc), (_Float16)(wb.y * asc),
                      (_Float16)(wb.z * asc), (_Float16)(wb.w * asc)};
    }
    // ---- D-row constants: gates i=0..3 of unit ud = 4*wv + lg
    const int ud = 4 * wv + lg;
    float wih_[4], bs_[4];
#pragma unroll
    for (int i = 0; i < 4; ++i) {
        const float scd = (i == 2) ? 2.0f * NL2E : NL2E;
        wih_[i] = w_ih[i * 32 + ud] * scd;
        bs_[i]  = (b_ih[i * 32 + ud] + b_hh[i * 32 + ud]) * scd;
    }

    float c = 0.0f;
    int p = 0;

    // ---- x staging: 512 thr x v2f covers 16 el x 64 floats
    const int es = tid >> 5;           // element 0..15
    const int j2 = (tid & 31) * 2;     // float offset 0..62
    const float* xbase = x + (size_t)barr[es] * TT + j2;

    // preload first chunk into regs
    v2f xpref = *reinterpret_cast<const v2f*>(xbase + ((maxL - 1) & ~63));

    for (int s = maxL - 1; s >= 0; --s) {
        if ((s & 63) == 63 || s == maxL - 1) {
            const int tb = s & ~63;
            // deposit prefetched chunk (regs -> LDS; no global latency here)
            *reinterpret_cast<v2f*>(&xls[es][j2]) = xpref;
            __syncthreads();
            // issue next chunk's load; drains at next step's barrier (~640cy)
            if (tb >= 64) xpref = *reinterpret_cast<const v2f*>(xbase + tb - 64);
        }
        // B fragment: h[k = 8*lg + j][e], contiguous 16B
        const f16x8 bf = *reinterpret_cast<const f16x8*>(&hb[p][e][lg * 8]);
        const float xe = xls[e][s & 63];
        f32x4 C;
#pragma unroll
        for (int i = 0; i < 4; ++i) C[i] = fmaf(wih_[i], xe, bs_[i]);
        const f32x4 D = __builtin_amdgcn_mfma_f32_16x16x32_f16(afr, bf, C, 0, 0, 0);
        const bool act = (s < Lme);

        // ---- cell update (bit-identical to r5/r6)
        const float Ei = fexp2(D[0]), Ef = fexp2(D[1]);
        const float Eg = fexp2(D[2]), Eo = fexp2(D[3]);
        const float R1 = frcp((1.0f + Ei) * (1.0f + Eg));
        const float ig = (1.0f - Eg) * R1;
        const float R2 = frcp((1.0f + Ef) * (1.0f + Eo));
        const float sf = (1.0f + Eo) * R2;
        const float so = (1.0f + Ef) * R2;
        const float cn = fmaf(sf, c, ig);
        c = act ? cn : c;
        const float tc = 1.0f - 2.0f * frcp(1.0f + fexp2(c * 2.8853900817779268f));
        const float hn = act ? (so * tc) : 0.0f;

        hb[p ^ 1][e][ud] = (_Float16)hn;
        __syncthreads();
        p ^= 1;
    }

    // ---- head: wave wv handles elements 2wv, 2wv+1
    for (int e2 = 2 * wv; e2 < 2 * wv + 2; ++e2) {
        float hf[32];
        const v8h* hp8 = reinterpret_cast<const v8h*>(&hb[p][e2][0]);
#pragma unroll
        for (int q4 = 0; q4 < 4; ++q4) {
            const v8h hh = hp8[q4];
#pragma unroll
            for (int j = 0; j < 8; ++j) hf[8 * q4 + j] = (float)hh[j];
        }
        float a = fc_b[lane];
        const v4f* fp = reinterpret_cast<const v4f*>(fc_w + lane * 32);
#pragma unroll
        for (int q4 = 0; q4 < 8; ++q4) {
            const v4f f = fp[q4];
            a = fmaf(f.x, hf[4 * q4 + 0], a);
            a = fmaf(f.y, hf[4 * q4 + 1], a);
            a = fmaf(f.z, hf[4 * q4 + 2], a);
            a = fmaf(f.w, hf[4 * q4 + 3], a);
        }
        float partial = felu(a) * fc2_w[lane];
#pragma unroll
        for (int m = 32; m >= 1; m >>= 1) partial += __shfl_xor(partial, m, 64);
        if (lane == 0) out[barr[e2]] = fsigmoid(partial + fc2_b[0]);
    }
}

extern "C" void kernel_launch(void* const* d_in, const int* in_sizes, int n_in,
                              void* d_out, int out_size, void* d_ws, size_t ws_size,
                              hipStream_t stream) {
    const float* x       = (const float*)d_in[0];
    const int*   lengths = (const int*)d_in[1];
    const float* w_ih    = (const float*)d_in[2];
    const float* w_hh    = (const float*)d_in[3];
    const float* b_ih    = (const float*)d_in[4];
    const float* b_hh    = (const float*)d_in[5];
    const float* fc_w    = (const float*)d_in[6];
    const float* fc_b    = (const float*)d_in[7];
    const float* fc2_w   = (const float*)d_in[8];
    const float* fc2_b   = (const float*)d_in[9];
    float* out = (float*)d_out;

    int* perm = nullptr;
    if (ws_size >= (size_t)BB * sizeof(int)) {
        perm = (int*)d_ws;
        hipLaunchKernelGGL(sort_by_len_kernel, dim3(1), dim3(256), 0, stream, lengths, perm);
    }
    hipLaunchKernelGGL(lstm_kernel, dim3(BB / GE), dim3(512), 0, stream,
                       x, lengths, w_ih, w_hh, b_ih, b_hh,
                       fc_w, fc_b, fc2_w, fc2_b, out, perm);
}

// Round 9
// 580.079 us; speedup vs baseline: 1.2927x; 1.0190x over previous
//
#include <hip/hip_runtime.h>

constexpr int BB = 4096;   // batch
constexpr int TT = 2048;   // time
constexpr int HH = 32;     // hidden
constexpr int GE = 16;     // elements per block (MFMA N)

typedef float v2f __attribute__((ext_vector_type(2)));
typedef float v4f __attribute__((ext_vector_type(4)));
typedef float f32x4 __attribute__((ext_vector_type(4)));
typedef _Float16 f16x8 __attribute__((ext_vector_type(8)));
typedef _Float16 v8h __attribute__((ext_vector_type(8)));

// ---------- fast math ----------
__device__ __forceinline__ float fexp2(float x) { return __builtin_amdgcn_exp2f(x); }
__device__ __forceinline__ float frcp(float x)  { return __builtin_amdgcn_rcpf(x); }
__device__ __forceinline__ float fsigmoid(float x) {
    return frcp(1.0f + fexp2(x * -1.4426950408889634f));
}
__device__ __forceinline__ float felu(float x) {
    return x > 0.0f ? x : (fexp2(x * 1.4426950408889634f) - 1.0f);
}

// ---------- kernel 1: counting sort of batch indices by length, descending ----------
__global__ void sort_by_len_kernel(const int* __restrict__ lengths, int* __restrict__ perm) {
    __shared__ int hist[TT];
    __shared__ int csum[256];
    const int tid = threadIdx.x;
    for (int i = tid; i < TT; i += 256) hist[i] = 0;
    __syncthreads();
    for (int i = tid; i < BB; i += 256) atomicAdd(&hist[TT - lengths[i]], 1);
    __syncthreads();
    const int base = tid * 8;
    int loc[8];
    int s = 0;
#pragma unroll
    for (int j = 0; j < 8; ++j) { loc[j] = hist[base + j]; s += loc[j]; }
    csum[tid] = s;
    __syncthreads();
    for (int off = 1; off < 256; off <<= 1) {
        int v = (tid >= off) ? csum[tid - off] : 0;
        __syncthreads();
        csum[tid] += v;
        __syncthreads();
    }
    int run = csum[tid] - s;
#pragma unroll
    for (int j = 0; j < 8; ++j) { int t = loc[j]; hist[base + j] = run; run += t; }
    __syncthreads();
    for (int i = tid; i < BB; i += 256) {
        int pos = atomicAdd(&hist[TT - lengths[i]], 1);
        perm[pos] = i;
    }
}

// ---------- kernel 2: MFMA group-batched backward LSTM, 8 waves (r8 + xe-batch) ----------
// r8 = 523us, wall/step 614cy, chain-bound. Post-barrier DS burst = 8 waves x
// (b128 h-read 12cy + b32 xe-read 6cy) ~ 144cy serialized on the CU DS pipe;
// the last wave's MFMA starts that late and the next barrier waits for it.
// This round removes the xe read from the burst (r7's intent, done right):
//   - 4-step unrolled body; ONE ds_read_b128 of xe per 4 steps; components
//     consumed as STATICALLY-indexed named scalars (r7 failed via dynamic
//     vector indexing -> cndmask chains; rule #20).
//   - xe in regs also un-fences the C-operand fmafs from the barrier: next
//     step's C can compute during the current trans chain.
//   - xls rows 66 -> 68 floats (272B: 16B-aligned for b128; bank e*4 -> only
//     the free 2-way e/e+8 alias).
// Pad steps to sTop=(maxL-1)|3 are act-gated inert (c,h frozen; h writes 0=0).
// Arithmetic bit-identical to r5/r6/r8 -> absmax must stay exactly 1.953125e-3.
// Mapping (verified r5/r6): wave w owns units 4w..4w+3; A row r=lane&15:
// gate s=r&3, unit 4w+(r>>2); k = 8*(lane>>4)+j for both operands;
// D row 4*lg+i = gates of unit ud=4w+lg, col e=lane&15.
__global__ __attribute__((amdgpu_flat_work_group_size(512, 512)))
void lstm_kernel(const float* __restrict__ x, const int* __restrict__ lengths,
                 const float* __restrict__ w_ih, const float* __restrict__ w_hh,
                 const float* __restrict__ b_ih, const float* __restrict__ b_hh,
                 const float* __restrict__ fc_w, const float* __restrict__ fc_b,
                 const float* __restrict__ fc2_w, const float* __restrict__ fc2_b,
                 float* __restrict__ out, const int* __restrict__ perm) {
    __shared__ __align__(16) _Float16 hb[2][GE][40];  // h, f16, padded rows, dbuf
    __shared__ __align__(16) float xls[GE][68];       // x chunk; 272B rows, 16B-aligned
    __shared__ int barr[GE];
    __shared__ int Llds[GE];
    __shared__ int maxLs;

    const int tid  = threadIdx.x;
    const int wv   = tid >> 6;        // wave 0..7
    const int lane = tid & 63;
    const int lg   = lane >> 4;       // lane group 0..3
    const int e    = lane & 15;       // element (MFMA col)

    const int g = blockIdx.x;
    if (tid < GE) {
        const int b = perm ? perm[GE * g + tid] : (GE * g + tid);
        barr[tid] = b;
        Llds[tid] = lengths[b];
    }
    for (int i = tid; i < 2 * GE * 40; i += 512) ((_Float16*)hb)[i] = (_Float16)0.0f;
    __syncthreads();
    if (tid == 0) {
        int m = 0;
        for (int i = 0; i < GE; ++i) m = max(m, Llds[i]);
        maxLs = m;
    }
    __syncthreads();
    const int maxL = maxLs;
    const int Lme  = Llds[e];

    const float NL2E = -1.4426950408889634f;

    // ---- A fragment (loaded once)
    const int r  = lane & 15;
    const int sg = r & 3;
    const int ua = 4 * wv + (r >> 2);
    const float asc = (sg == 2) ? 2.0f * NL2E : NL2E;   // g row: tanh scaling
    f16x8 afr;
    {
        const v4f* wp = reinterpret_cast<const v4f*>(w_hh + (sg * 32 + ua) * 32 + 8 * lg);
        const v4f wa = wp[0], wb = wp[1];
        afr = (f16x8){(_Float16)(wa.x * asc), (_Float16)(wa.y * asc),
                      (_Float16)(wa.z * asc), (_Float16)(wa.w * asc),
                      (_Float16)(wb.x * asc), (_Float16)(wb.y * asc),
                      (_Float16)(wb.z * asc), (_Float16)(wb.w * asc)};
    }
    // ---- D-row constants: gates i=0..3 of unit ud = 4*wv + lg
    const int ud = 4 * wv + lg;
    float wih_[4], bs_[4];
#pragma unroll
    for (int i = 0; i < 4; ++i) {
        const float scd = (i == 2) ? 2.0f * NL2E : NL2E;
        wih_[i] = w_ih[i * 32 + ud] * scd;
        bs_[i]  = (b_ih[i * 32 + ud] + b_hh[i * 32 + ud]) * scd;
    }

    float c = 0.0f;
    int p = 0;

    // ---- x staging: 512 thr x v2f covers 16 el x 64 floats
    const int es = tid >> 5;           // element 0..15
    const int j2 = (tid & 31) * 2;     // float offset 0..62
    const float* xbase = x + (size_t)barr[es] * TT + j2;

    const int sTop = (maxL - 1) | 3;   // pad to 4-step blocks; pad steps inert

    // preload first chunk into regs
    v2f xpref = *reinterpret_cast<const v2f*>(xbase + (sTop & ~63));

    for (int sb = sTop; sb >= 3; sb -= 4) {
        if ((sb & 63) == 63 || sb == sTop) {
            const int tb = sb & ~63;
            // deposit prefetched chunk (regs -> LDS; no global latency here)
            *reinterpret_cast<v2f*>(&xls[es][j2]) = xpref;
            __syncthreads();
            // issue next chunk's load; drains over the next ~64 steps
            if (tb >= 64) xpref = *reinterpret_cast<const v2f*>(xbase + tb - 64);
        }
        // one b128 covers xe for the 4 steps of this block (static components)
        const v4f x4 = *reinterpret_cast<const v4f*>(&xls[e][(sb & 63) - 3]);
#pragma unroll
        for (int k = 0; k < 4; ++k) {
            const int s   = sb - k;
            const float xe = x4[3 - k];            // static index (k is unrolled)
            // B fragment: h[k = 8*lg + j][e], contiguous 16B
            const f16x8 bf = *reinterpret_cast<const f16x8*>(&hb[p][e][lg * 8]);
            f32x4 C;
#pragma unroll
            for (int i = 0; i < 4; ++i) C[i] = fmaf(wih_[i], xe, bs_[i]);
            const f32x4 D = __builtin_amdgcn_mfma_f32_16x16x32_f16(afr, bf, C, 0, 0, 0);
            const bool act = (s < Lme);

            // ---- cell update (bit-identical to r5/r6/r8)
            const float Ei = fexp2(D[0]), Ef = fexp2(D[1]);
            const float Eg = fexp2(D[2]), Eo = fexp2(D[3]);
            const float R1 = frcp((1.0f + Ei) * (1.0f + Eg));
            const float ig = (1.0f - Eg) * R1;
            const float R2 = frcp((1.0f + Ef) * (1.0f + Eo));
            const float sf = (1.0f + Eo) * R2;
            const float so = (1.0f + Ef) * R2;
            const float cn = fmaf(sf, c, ig);
            c = act ? cn : c;
            const float tc = 1.0f - 2.0f * frcp(1.0f + fexp2(c * 2.8853900817779268f));
            const float hn = act ? (so * tc) : 0.0f;

            hb[p ^ 1][e][ud] = (_Float16)hn;
            __syncthreads();
            p ^= 1;
        }
    }

    // ---- head: wave wv handles elements 2wv, 2wv+1
    for (int e2 = 2 * wv; e2 < 2 * wv + 2; ++e2) {
        float hf[32];
        const v8h* hp8 = reinterpret_cast<const v8h*>(&hb[p][e2][0]);
#pragma unroll
        for (int q4 = 0; q4 < 4; ++q4) {
            const v8h hh = hp8[q4];
#pragma unroll
            for (int j = 0; j < 8; ++j) hf[8 * q4 + j] = (float)hh[j];
        }
        float a = fc_b[lane];
        const v4f* fp = reinterpret_cast<const v4f*>(fc_w + lane * 32);
#pragma unroll
        for (int q4 = 0; q4 < 8; ++q4) {
            const v4f f = fp[q4];
            a = fmaf(f.x, hf[4 * q4 + 0], a);
            a = fmaf(f.y, hf[4 * q4 + 1], a);
            a = fmaf(f.z, hf[4 * q4 + 2], a);
            a = fmaf(f.w, hf[4 * q4 + 3], a);
        }
        float partial = felu(a) * fc2_w[lane];
#pragma unroll
        for (int m = 32; m >= 1; m >>= 1) partial += __shfl_xor(partial, m, 64);
        if (lane == 0) out[barr[e2]] = fsigmoid(partial + fc2_b[0]);
    }
}

extern "C" void kernel_launch(void* const* d_in, const int* in_sizes, int n_in,
                              void* d_out, int out_size, void* d_ws, size_t ws_size,
                              hipStream_t stream) {
    const float* x       = (const float*)d_in[0];
    const int*   lengths = (const int*)d_in[1];
    const float* w_ih    = (const float*)d_in[2];
    const float* w_hh    = (const float*)d_in[3];
    const float* b_ih    = (const float*)d_in[4];
    const float* b_hh    = (const float*)d_in[5];
    const float* fc_w    = (const float*)d_in[6];
    const float* fc_b    = (const float*)d_in[7];
    const float* fc2_w   = (const float*)d_in[8];
    const float* fc2_b   = (const float*)d_in[9];
    float* out = (float*)d_out;

    int* perm = nullptr;
    if (ws_size >= (size_t)BB * sizeof(int)) {
        perm = (int*)d_ws;
        hipLaunchKernelGGL(sort_by_len_kernel, dim3(1), dim3(256), 0, stream, lengths, perm);
    }
    hipLaunchKernelGGL(lstm_kernel, dim3(BB / GE), dim3(512), 0, stream,
                       x, lengths, w_ih, w_hh, b_ih, b_hh,
                       fc_w, fc_b, fc2_w, fc2_b, out, perm);
}